// Round 12
// baseline (235.718 us; speedup 1.0000x reference)
//
#include <hip/hip_runtime.h>
#include <math.h>

constexpr int KK = 2;
constexpr int HH = 4;
constexpr int NN = 4096;
constexpr int DD = 64;
constexpr int OO = 64;
constexpr int NU = 4000;
constexpr int CC = 2;
constexpr int JSPLIT = 4;
constexpr float LOG2E = 1.44269504088896340736f;

typedef float vf4 __attribute__((ext_vector_type(4)));
typedef float vf2 __attribute__((ext_vector_type(2)));

__device__ __forceinline__ float fexp2(float x) {
#if __has_builtin(__builtin_amdgcn_exp2f)
  return __builtin_amdgcn_exp2f(x);
#else
  return exp2f(x);
#endif
}
__device__ __forceinline__ float frcp(float x) {
#if __has_builtin(__builtin_amdgcn_rcpf)
  return __builtin_amdgcn_rcpf(x);
#else
  return 1.0f / x;
#endif
}
__device__ __forceinline__ float ftanh(float x) {
  float e = fexp2(x * (2.0f * LOG2E));
  return 1.0f - 2.0f * frcp(e + 1.0f);
}

// ---------------------------------------------------------------------------
// Phase 1 (R9-proven 64-row version): per (k,h): hp = h @ w; per node:
//   srcAA[kh][i] = {2^src', 2^(0.2 src')}
//   Bp[kh][j]=2^dst', B5p[kh][j]=2^(0.2 dst'), g0p/g1p[kh][j]=hp_j.fc_w_c
// exp2(leaky(s)) == max(A*B, A5*B5)  (exact identity, validated R9-R11).
// ---------------------------------------------------------------------------
__global__ __launch_bounds__(256) void gat_phase1(
    const float* __restrict__ hsrc, const float* __restrict__ w,
    const float* __restrict__ a_src, const float* __restrict__ a_dst,
    const float* __restrict__ fc_w,
    float* __restrict__ srcAA, float* __restrict__ Bp,
    float* __restrict__ B5p, float* __restrict__ g0p,
    float* __restrict__ g1p) {
  const int kh = blockIdx.y;  // 0..7
  const int k = kh >> 2;
  const int i0 = blockIdx.x * 64;
  const int tid = threadIdx.x;

  __shared__ float h_s[DD][68];
  __shared__ float w_s[DD][OO];
  __shared__ float part[4][64][17];  // [val][row][og], padded

  {
    const vf4* wp = (const vf4*)(w + (size_t)kh * DD * OO);
    vf4* ws4 = (vf4*)w_s;
    for (int t = tid; t < DD * OO / 4; t += 256) ws4[t] = wp[t];
  }
  for (int t = tid; t < 1024; t += 256) {
    const int row = t >> 4;
    const int f4 = (t & 15) * 4;
    vf4 v = *(const vf4*)(hsrc + (size_t)(i0 + row) * DD + f4);
    h_s[f4 + 0][row] = v.x;
    h_s[f4 + 1][row] = v.y;
    h_s[f4 + 2][row] = v.z;
    h_s[f4 + 3][row] = v.w;
  }
  __syncthreads();

  const int og = tid & 15;
  const int rg = tid >> 4;
  const int o0 = og * 4;
  const int r0 = rg * 4;

  float hp[4][4];
#pragma unroll
  for (int j = 0; j < 4; ++j)
#pragma unroll
    for (int u = 0; u < 4; ++u) hp[j][u] = 0.0f;

#pragma unroll 8
  for (int f = 0; f < DD; ++f) {
    vf4 hv = *(const vf4*)&h_s[f][r0];
    vf4 wv = *(const vf4*)&w_s[f][o0];
    hp[0][0] = fmaf(hv.x, wv.x, hp[0][0]);
    hp[0][1] = fmaf(hv.x, wv.y, hp[0][1]);
    hp[0][2] = fmaf(hv.x, wv.z, hp[0][2]);
    hp[0][3] = fmaf(hv.x, wv.w, hp[0][3]);
    hp[1][0] = fmaf(hv.y, wv.x, hp[1][0]);
    hp[1][1] = fmaf(hv.y, wv.y, hp[1][1]);
    hp[1][2] = fmaf(hv.y, wv.z, hp[1][2]);
    hp[1][3] = fmaf(hv.y, wv.w, hp[1][3]);
    hp[2][0] = fmaf(hv.z, wv.x, hp[2][0]);
    hp[2][1] = fmaf(hv.z, wv.y, hp[2][1]);
    hp[2][2] = fmaf(hv.z, wv.z, hp[2][2]);
    hp[2][3] = fmaf(hv.z, wv.w, hp[2][3]);
    hp[3][0] = fmaf(hv.w, wv.x, hp[3][0]);
    hp[3][1] = fmaf(hv.w, wv.y, hp[3][1]);
    hp[3][2] = fmaf(hv.w, wv.z, hp[3][2]);
    hp[3][3] = fmaf(hv.w, wv.w, hp[3][3]);
  }

  float as[4], ad[4], f0[4], f1[4];
#pragma unroll
  for (int u = 0; u < 4; ++u) {
    as[u] = a_src[kh * OO + o0 + u];
    ad[u] = a_dst[kh * OO + o0 + u];
    f0[u] = fc_w[0 * (KK * OO) + k * OO + o0 + u];
    f1[u] = fc_w[1 * (KK * OO) + k * OO + o0 + u];
  }

#pragma unroll
  for (int j = 0; j < 4; ++j) {
    float sp = 0.0f, dp = 0.0f, g0 = 0.0f, g1 = 0.0f;
#pragma unroll
    for (int u = 0; u < 4; ++u) {
      float v = hp[j][u];
      float t = ftanh(v);
      sp = fmaf(t, as[u], sp);
      dp = fmaf(t, ad[u], dp);
      g0 = fmaf(v, f0[u], g0);
      g1 = fmaf(v, f1[u], g1);
    }
    part[0][r0 + j][og] = sp;
    part[1][r0 + j][og] = dp;
    part[2][r0 + j][og] = g0;
    part[3][r0 + j][og] = g1;
  }
  __syncthreads();

  {  // thread = (row j2, val): sum 16 og-partials, transform, write out
    const int val = tid & 3;
    const int j2 = tid >> 2;
    const float* pr = &part[val][j2][0];
    vf4 s0 = *(const vf4*)(pr + 0);
    vf4 s1 = *(const vf4*)(pr + 4);
    vf4 s2 = *(const vf4*)(pr + 8);
    vf4 s3 = *(const vf4*)(pr + 12);
    vf4 t4 = s0 + s1 + s2 + s3;
    float sum = t4.x + t4.y + t4.z + t4.w;
    const size_t idx = (size_t)kh * NN + i0 + j2;
    if (val == 0) {
      float sp = sum * LOG2E;
      vf2 v = {fexp2(sp), fexp2(0.2f * sp)};
      *(vf2*)(srcAA + idx * 2) = v;
    } else if (val == 1) {
      float dp = sum * LOG2E;
      Bp[idx] = fexp2(dp);
      B5p[idx] = fexp2(0.2f * dp);
    } else if (val == 2) {
      g0p[idx] = sum;
    } else {
      g1p[idx] = sum;
    }
  }
}

// ---------------------------------------------------------------------------
// Phase 2: grid (NU/4, K*JSPLIT), block = 64 threads = ONE wave.
// Wave = 4 rows x 1024-j chunk (4 tiles of 256 j), lane = j-quad: every
// load (adj, B, B5, g0, g1) is dense vf4 (1 KB/instr). No LDS, no
// __syncthreads, no cross-wave coupling: 8000 independent single-wave
// blocks (~31 waves/CU demand) to bury latency. Adj prefetched 1 tile
// ahead; planes double-buffered over h.
//   e = max(A*B, A5*B5); pa = e*adj; l += pa; a_c += pa*g_c
// Butterfly(48) -> lane0 writes partials P[k][chunk][h][{l,a0,a1}][i].
// ---------------------------------------------------------------------------
__global__ __launch_bounds__(64) void gat_phase2(
    const float* __restrict__ adj, const float* __restrict__ srcAA,
    const float* __restrict__ Bp, const float* __restrict__ B5p,
    const float* __restrict__ g0p, const float* __restrict__ g1p,
    float* __restrict__ P) {
  const int k = blockIdx.y >> 2;
  const int chunk = blockIdx.y & 3;
  const int r0 = blockIdx.x * 4;
  const int lane = threadIdx.x;

  // wave-uniform A factors
  float A[4][4], A5[4][4];  // [r][h]
#pragma unroll
  for (int h = 0; h < 4; ++h) {
    const float* base = srcAA + ((size_t)(k * HH + h) * NN + r0) * 2;
#pragma unroll
    for (int r = 0; r < 4; ++r) {
      A[r][h] = base[r * 2 + 0];
      A5[r][h] = base[r * 2 + 1];
    }
  }

  float l[4][4], a0[4][4], a1[4][4];  // [r][h]
#pragma unroll
  for (int r = 0; r < 4; ++r)
#pragma unroll
    for (int h = 0; h < 4; ++h) {
      l[r][h] = 0.0f;
      a0[r][h] = 0.0f;
      a1[r][h] = 0.0f;
    }

  const float* adjk = adj + (size_t)k * NN * NN;
  const int jw = chunk * 1024 + lane * 4;

  vf4 avc[4], avn[4];
#pragma unroll
  for (int r = 0; r < 4; ++r)
    avc[r] = *(const vf4*)(adjk + (size_t)(r0 + r) * NN + jw);

#pragma unroll 1
  for (int t = 0; t < 4; ++t) {
    const int j = jw + t * 256;
    if (t < 3) {  // prefetch next tile's adj
#pragma unroll
      for (int r = 0; r < 4; ++r)
        avn[r] = *(const vf4*)(adjk + (size_t)(r0 + r) * NN + j + 256);
    }
    size_t pb = (size_t)(k * HH + 0) * NN + j;
    vf4 bC = *(const vf4*)(Bp + pb);
    vf4 b5C = *(const vf4*)(B5p + pb);
    vf4 g0C = *(const vf4*)(g0p + pb);
    vf4 g1C = *(const vf4*)(g1p + pb);
#pragma unroll
    for (int h = 0; h < 4; ++h) {
      vf4 b = bC, b5 = b5C, g0 = g0C, g1 = g1C;
      if (h < 3) {
        size_t pn = (size_t)(k * HH + h + 1) * NN + j;
        bC = *(const vf4*)(Bp + pn);
        b5C = *(const vf4*)(B5p + pn);
        g0C = *(const vf4*)(g0p + pn);
        g1C = *(const vf4*)(g1p + pn);
      }
      vf2 blo = {b.x, b.y}, bhi = {b.z, b.w};
      vf2 b5lo = {b5.x, b5.y}, b5hi = {b5.z, b5.w};
#pragma unroll
      for (int r = 0; r < 4; ++r) {
        vf2 elo = __builtin_elementwise_max(blo * A[r][h], b5lo * A5[r][h]);
        vf2 ehi = __builtin_elementwise_max(bhi * A[r][h], b5hi * A5[r][h]);
        float p0 = elo.x * avc[r].x;
        float p1 = elo.y * avc[r].y;
        float p2 = ehi.x * avc[r].z;
        float p3 = ehi.y * avc[r].w;
        l[r][h] += (p0 + p1) + (p2 + p3);
        a0[r][h] = fmaf(p0, g0.x, fmaf(p1, g0.y, fmaf(p2, g0.z, fmaf(p3, g0.w, a0[r][h]))));
        a1[r][h] = fmaf(p0, g1.x, fmaf(p1, g1.y, fmaf(p2, g1.z, fmaf(p3, g1.w, a1[r][h]))));
      }
    }
#pragma unroll
    for (int r = 0; r < 4; ++r) avc[r] = avn[r];
  }

  // butterfly across 64 lanes (48 scalars)
#pragma unroll
  for (int r = 0; r < 4; ++r)
#pragma unroll
    for (int h = 0; h < 4; ++h) {
      float x0 = l[r][h], x1 = a0[r][h], x2 = a1[r][h];
#pragma unroll
      for (int off = 32; off > 0; off >>= 1) {
        x0 += __shfl_xor(x0, off, 64);
        x1 += __shfl_xor(x1, off, 64);
        x2 += __shfl_xor(x2, off, 64);
      }
      l[r][h] = x0;
      a0[r][h] = x1;
      a1[r][h] = x2;
    }

  if (lane == 0) {
#pragma unroll
    for (int r = 0; r < 4; ++r)
#pragma unroll
      for (int h = 0; h < 4; ++h) {
        // P layout: [k][chunk][h][{l,a0,a1}][i]
        size_t base =
            (((size_t)(k * JSPLIT + chunk) * HH + h) * 3) * NU + (r0 + r);
        P[base] = l[r][h];
        P[base + NU] = a0[r][h];
        P[base + 2 * (size_t)NU] = a1[r][h];
      }
  }
}

// ---------------------------------------------------------------------------
// Phase 3: combine chunk partials, divide, mean heads, sum kinds, +bias,
// log_softmax over C=2.
// ---------------------------------------------------------------------------
__global__ __launch_bounds__(256) void gat_phase3(
    const float* __restrict__ P, const float* __restrict__ fc_b,
    float* __restrict__ out) {
  const int i = blockIdx.x * 256 + threadIdx.x;
  if (i >= NU) return;
  float l0 = fc_b[0], l1 = fc_b[1];
#pragma unroll
  for (int k = 0; k < KK; ++k) {
#pragma unroll
    for (int q = 0; q < HH; ++q) {
      float ls = 0.0f, a0 = 0.0f, a1 = 0.0f;
#pragma unroll
      for (int ch = 0; ch < JSPLIT; ++ch) {
        size_t b = (((size_t)(k * JSPLIT + ch) * HH + q) * 3) * NU + i;
        ls += P[b];
        a0 += P[b + NU];
        a1 += P[b + 2 * (size_t)NU];
      }
      float inv = 1.0f / ls;
      l0 = fmaf(0.25f * a0, inv, l0);
      l1 = fmaf(0.25f * a1, inv, l1);
    }
  }
  float m = fmaxf(l0, l1);
  float lse = m + logf(expf(l0 - m) + expf(l1 - m));
  out[i * CC + 0] = l0 - lse;
  out[i * CC + 1] = l1 - lse;
}

extern "C" void kernel_launch(void* const* d_in, const int* in_sizes, int n_in,
                              void* d_out, int out_size, void* d_ws, size_t ws_size,
                              hipStream_t stream) {
  const float* hsrc  = (const float*)d_in[0];  // (1,4096,64)
  const float* hadj  = (const float*)d_in[1];  // (2,1,4096,4096)
  const float* w     = (const float*)d_in[2];  // (2,4,64,64)
  const float* a_src = (const float*)d_in[3];  // (2,4,64,1)
  const float* a_dst = (const float*)d_in[4];  // (2,4,64,1)
  const float* fc_w  = (const float*)d_in[5];  // (2,128)
  const float* fc_b  = (const float*)d_in[6];  // (2,)
  float* out = (float*)d_out;                  // (1,4000,2) fp32

  char* ws = (char*)d_ws;
  float* srcAA = (float*)(ws + 0);        // K*H*N*2 (256 KB)
  float* Bp    = (float*)(ws + 262144);   // K*H*N   (128 KB each)
  float* B5p   = (float*)(ws + 393216);
  float* g0p   = (float*)(ws + 524288);
  float* g1p   = (float*)(ws + 655360);
  float* P     = (float*)(ws + 786432);   // K*JSPLIT*H*3*NU (~1.5 MB)

  dim3 g1(NN / 64, KK * HH);
  gat_phase1<<<g1, 256, 0, stream>>>(hsrc, w, a_src, a_dst, fc_w,
                                     srcAA, Bp, B5p, g0p, g1p);
  dim3 g2(NU / 4, KK * JSPLIT);
  gat_phase2<<<g2, 64, 0, stream>>>(hadj, srcAA, Bp, B5p, g0p, g1p, P);
  gat_phase3<<<(NU + 255) / 256, 256, 0, stream>>>(P, fc_b, out);
}